// Round 2
// baseline (395.482 us; speedup 1.0000x reference)
//
#include <hip/hip_runtime.h>
#include <hip/hip_fp16.h>

#define B_  8
#define S_  2048
#define D_  512
#define K_  4096
#define N_  (B_ * S_)          // 16384 rows
#define NCB (K_ / 128)         // 32 code-blocks

typedef _Float16 half8  __attribute__((ext_vector_type(8)));
typedef _Float16 half4  __attribute__((ext_vector_type(4)));
typedef float    floatx4 __attribute__((ext_vector_type(4)));

// ---- workspace layout (bytes) ----
#define OFF_PV  0                          // partial min values  [N_][32] float (2 MB)
#define OFF_PI  (N_ * NCB * 4)             // partial min indices [N_][32] int   (2 MB)
#define OFF_EN  (OFF_PI + N_ * NCB * 4)    // enorm [K_] float
#define OFF_ZN  (OFF_EN + K_ * 4)          // znorm [N_] float
#define OFF_CNT (OFF_ZN + N_ * 4)          // counts [K_] int
#define OFF_BL  (OFF_CNT + K_ * 4)         // blockLoss [4096] float

// ---------------- kernel 1: row norms (used for both codebook and z) ----------------
// Exact bitwise match to np is NOT required: any fp32-level difference vs np's
// pairwise sum is an exact multiple of the local ulp, which rigidly shifts the
// whole row's distance lattice and preserves the argmin/tie structure.
__global__ void vq_norms_kernel(const float* __restrict__ x, float* __restrict__ nrm) {
    int lane = threadIdx.x & 63;
    int row  = blockIdx.x * 4 + (threadIdx.x >> 6);
    const float* r = x + (size_t)row * D_;
    float s = 0.f;
    for (int j = lane; j < D_; j += 64) { float v = r[j]; s += v * v; }
    #pragma unroll
    for (int m = 1; m < 64; m <<= 1) s += __shfl_xor(s, m, 64);
    if (lane == 0) nrm[row] = s;
}

// ---------------- kernel 2: fused distance GEMM + per-tile argmin ----------------
// d[m][c] = fp32(fp32(znorm[m] + enorm[c]) - 2 * dot) on np's fp32 lattice.
// dot via fp16 split: z = zh+zl; e' = 64*e (exact) = eh+el (both fp16 NORMAL range);
// acc = zh*eh + zh*el + zl*eh + zl*el (4 MFMA terms); dot = acc * 2^-6 (exact).
#define BM  128
#define BN  128
#define BK  32
#define LDH 40   // padded LDS row stride (f16 elems)

__global__ __launch_bounds__(256, 2)
void vq_dist_kernel(const float* __restrict__ z, const float* __restrict__ cb,
                    const float* __restrict__ enorm, const float* __restrict__ znorm,
                    float* __restrict__ pV, int* __restrict__ pI) {
    __shared__ _Float16 sAh[BM * LDH], sAl[BM * LDH];
    __shared__ _Float16 sBh[BN * LDH], sBl[BN * LDH];
    __shared__ float sE[BN];
    __shared__ float sZn[BM];
    __shared__ float candV[2][BM];
    __shared__ int   candI[2][BM];

    const int t    = threadIdx.x;
    const int mblk = blockIdx.x;
    const int cblk = blockIdx.y;
    const int m0   = mblk * BM;
    const int c0   = cblk * BN;

    if (t < BN) sE[t]  = enorm[c0 + t];
    if (t < BM) sZn[t] = znorm[m0 + t];

    const int lane = t & 63, wid = t >> 6;
    const int wr = wid & 1, wc = wid >> 1;     // 2x2 waves over 128x128
    const int qd = lane >> 4, nl = lane & 15;

    floatx4 acc[4][4];
    #pragma unroll
    for (int i = 0; i < 4; i++)
        #pragma unroll
        for (int j = 0; j < 4; j++) acc[i][j] = (floatx4)0.f;

    // staging map: thread t, rep i -> row = (t>>3) + 32*i, 4-float chunk col = (t&7)*4
    const int srow0 = t >> 3;
    const int sc4   = (t & 7) * 4;
    const float* zbase = z  + (size_t)m0 * D_;
    const float* cbase = cb + (size_t)c0 * D_;

    for (int kk = 0; kk < D_; kk += BK) {
        __syncthreads();   // protect LDS from previous iteration's readers
        #pragma unroll
        for (int i = 0; i < 4; i++) {
            const int row = srow0 + 32 * i;
            const float4 av = *(const float4*)(zbase + (size_t)row * D_ + kk + sc4);
            const float4 bv = *(const float4*)(cbase + (size_t)row * D_ + kk + sc4);
            float a[4] = {av.x, av.y, av.z, av.w};
            float b[4] = {bv.x * 64.0f, bv.y * 64.0f, bv.z * 64.0f, bv.w * 64.0f};
            half4 ah, al, bh, bl;
            #pragma unroll
            for (int j = 0; j < 4; j++) {
                _Float16 h = (_Float16)a[j]; ah[j] = h; al[j] = (_Float16)(a[j] - (float)h);
                _Float16 g = (_Float16)b[j]; bh[j] = g; bl[j] = (_Float16)(b[j] - (float)g);
            }
            *(half4*)&sAh[row * LDH + sc4] = ah;
            *(half4*)&sAl[row * LDH + sc4] = al;
            *(half4*)&sBh[row * LDH + sc4] = bh;
            *(half4*)&sBl[row * LDH + sc4] = bl;
        }
        __syncthreads();

        half8 a_h[4], a_l[4], b_h[4], b_l[4];
        #pragma unroll
        for (int s = 0; s < 4; s++) {
            const int ar = wr * 64 + s * 16 + nl;
            const int br = wc * 64 + s * 16 + nl;
            a_h[s] = *(const half8*)&sAh[ar * LDH + qd * 8];
            a_l[s] = *(const half8*)&sAl[ar * LDH + qd * 8];
            b_h[s] = *(const half8*)&sBh[br * LDH + qd * 8];
            b_l[s] = *(const half8*)&sBl[br * LDH + qd * 8];
        }
        #pragma unroll
        for (int i = 0; i < 4; i++)
            #pragma unroll
            for (int j = 0; j < 4; j++) {
                acc[i][j] = __builtin_amdgcn_mfma_f32_16x16x32_f16(a_h[i], b_h[j], acc[i][j], 0, 0, 0);
                acc[i][j] = __builtin_amdgcn_mfma_f32_16x16x32_f16(a_h[i], b_l[j], acc[i][j], 0, 0, 0);
                acc[i][j] = __builtin_amdgcn_mfma_f32_16x16x32_f16(a_l[i], b_h[j], acc[i][j], 0, 0, 0);
                acc[i][j] = __builtin_amdgcn_mfma_f32_16x16x32_f16(a_l[i], b_l[j], acc[i][j], 0, 0, 0);
            }
    }

    // epilogue: d = (znorm + enorm) - 2*dot with np's fp32 rounding sequence.
    // (znorm+enorm) rounds once; 2*dot is exact (x2 and x2^-6 are exponent ops);
    // the subtract rounds once -> same lattice as np.
    #pragma unroll
    for (int sm = 0; sm < 4; sm++) {
        #pragma unroll
        for (int reg = 0; reg < 4; reg++) {
            const int rm = wr * 64 + sm * 16 + qd * 4 + reg;
            const float zn = sZn[rm];
            float bv = 1e30f; int bi = 0x7fffffff;
            #pragma unroll
            for (int sn = 0; sn < 4; sn++) {
                const int cl = wc * 64 + sn * 16 + nl;
                const float dot = acc[sm][sn][reg] * 0.015625f;  // /64, exact
                const float s2  = zn + sE[cl];                   // rounds (np: znorm+enorm)
                const float v   = s2 - 2.0f * dot;               // rounds once
                const int ci = c0 + cl;
                if (v < bv || (v == bv && ci < bi)) { bv = v; bi = ci; }
            }
            #pragma unroll
            for (int msk = 1; msk <= 8; msk <<= 1) {
                const float ov = __shfl_xor(bv, msk, 64);
                const int   oi = __shfl_xor(bi, msk, 64);
                if (ov < bv || (ov == bv && oi < bi)) { bv = ov; bi = oi; }
            }
            if (nl == 0) { candV[wc][rm] = bv; candI[wc][rm] = bi; }
        }
    }
    __syncthreads();
    if (t < BM) {
        float v0 = candV[0][t]; int i0 = candI[0][t];
        const float v1 = candV[1][t]; const int i1 = candI[1][t];
        if (v1 < v0 || (v1 == v0 && i1 < i0)) { v0 = v1; i0 = i1; }
        pV[(size_t)(m0 + t) * NCB + cblk] = v0;
        pI[(size_t)(m0 + t) * NCB + cblk] = i0;
    }
}

// ---------------- kernel 3: final argmin + gather + loss partials + histogram ----------------
__global__ __launch_bounds__(256)
void vq_gather_kernel(const float* __restrict__ z, const float* __restrict__ cb,
                      const float* __restrict__ pV, const int* __restrict__ pI,
                      float* __restrict__ out_zq, float* __restrict__ out_idx,
                      int* __restrict__ counts, float* __restrict__ blockLoss) {
    const int lane = threadIdx.x & 63, wid = threadIdx.x >> 6;
    const int m = blockIdx.x * 4 + wid;

    float v = 1e30f; int idx = 0x7fffffff;
    if (lane < NCB) { v = pV[(size_t)m * NCB + lane]; idx = pI[(size_t)m * NCB + lane]; }
    #pragma unroll
    for (int msk = 1; msk <= 16; msk <<= 1) {
        const float ov = __shfl_xor(v, msk, 64);
        const int   oi = __shfl_xor(idx, msk, 64);
        if (ov < v || (ov == v && oi < idx)) { v = ov; idx = oi; }
    }
    idx = __shfl(idx, 0, 64);

    const float4* qrow = (const float4*)(cb + (size_t)idx * D_);
    const float4* zrow = (const float4*)(z  + (size_t)m   * D_);
    float4*       orow = (float4*)(out_zq + (size_t)m * D_);
    float lsum = 0.f;
    #pragma unroll
    for (int i = 0; i < 2; i++) {
        const int j = lane + i * 64;
        const float4 q  = qrow[j];
        const float4 zv = zrow[j];
        float4 o;
        o.x = zv.x + (q.x - zv.x); o.y = zv.y + (q.y - zv.y);
        o.z = zv.z + (q.z - zv.z); o.w = zv.w + (q.w - zv.w);
        orow[j] = o;
        const float dx = zv.x - q.x, dy = zv.y - q.y, dz = zv.z - q.z, dw = zv.w - q.w;
        lsum += dx * dx + dy * dy + dz * dz + dw * dw;
    }
    #pragma unroll
    for (int msk = 1; msk < 64; msk <<= 1) lsum += __shfl_xor(lsum, msk, 64);

    if (lane == 0) {
        out_idx[m] = (float)idx;
        atomicAdd(&counts[idx], 1);
    }
    __shared__ float wl[4];
    if (lane == 0) wl[wid] = lsum;
    __syncthreads();
    if (threadIdx.x == 0) blockLoss[blockIdx.x] = wl[0] + wl[1] + wl[2] + wl[3];
}

// ---------------- kernel 4: scalars (loss, perplexity) ----------------
__global__ void vq_final_kernel(const int* __restrict__ counts,
                                const float* __restrict__ blockLoss,
                                float* __restrict__ out_loss, float* __restrict__ out_ppl) {
    __shared__ float sl[256], se[256];
    const int t = threadIdx.x;
    float ls = 0.f, es = 0.f;
    for (int i = t; i < N_ / 4; i += 256) ls += blockLoss[i];
    for (int k = t; k < K_; k += 256) {
        const float p = (float)counts[k] / (float)N_;
        es += p * logf(p + 1e-10f);
    }
    sl[t] = ls; se[t] = es;
    __syncthreads();
    for (int s = 128; s > 0; s >>= 1) {
        if (t < s) { sl[t] += sl[t + s]; se[t] += se[t + s]; }
        __syncthreads();
    }
    if (t == 0) {
        out_loss[0] = 0.25f * (sl[0] / (float)((size_t)N_ * D_));
        out_ppl[0]  = expf(-se[0]);
    }
}

extern "C" void kernel_launch(void* const* d_in, const int* in_sizes, int n_in,
                              void* d_out, int out_size, void* d_ws, size_t ws_size,
                              hipStream_t stream) {
    const float* z  = (const float*)d_in[0];
    const float* cb = (const float*)d_in[1];
    float* out = (float*)d_out;

    char* ws = (char*)d_ws;
    float* pV        = (float*)(ws + OFF_PV);
    int*   pI        = (int*)  (ws + OFF_PI);
    float* enorm     = (float*)(ws + OFF_EN);
    float* znorm     = (float*)(ws + OFF_ZN);
    int*   counts    = (int*)  (ws + OFF_CNT);
    float* blockLoss = (float*)(ws + OFF_BL);

    float* out_zq   = out;                         // [N_*D_]
    float* out_loss = out + (size_t)N_ * D_;       // [1]
    float* out_idx  = out_loss + 1;                // [N_]
    float* out_ppl  = out_idx + N_;                // [1]

    hipMemsetAsync(counts, 0, K_ * sizeof(int), stream);

    vq_norms_kernel<<<K_ / 4, 256, 0, stream>>>(cb, enorm);
    vq_norms_kernel<<<N_ / 4, 256, 0, stream>>>(z, znorm);

    dim3 grid(N_ / BM, K_ / BN);
    vq_dist_kernel<<<grid, 256, 0, stream>>>(z, cb, enorm, znorm, pV, pI);

    vq_gather_kernel<<<N_ / 4, 256, 0, stream>>>(z, cb, pV, pI, out_zq, out_idx,
                                                 counts, blockLoss);

    vq_final_kernel<<<1, 256, 0, stream>>>(counts, blockLoss, out_loss, out_ppl);
}

// Round 3
// 323.256 us; speedup vs baseline: 1.2234x; 1.2234x over previous
//
#include <hip/hip_runtime.h>
#include <hip/hip_fp16.h>
#include <stdint.h>

#define B_  8
#define S_  2048
#define D_  512
#define K_  4096
#define N_  (B_ * S_)          // 16384 rows
#define NCB (K_ / 128)         // 32 code-blocks
#define NKB (D_ / 32)          // 16 k-blocks

typedef _Float16 half8  __attribute__((ext_vector_type(8)));
typedef float    floatx4 __attribute__((ext_vector_type(4)));

// ---- workspace layout (bytes) ----
#define OFF_PV  0                                  // [N_][32] float  (2 MB)
#define OFF_PI  (OFF_PV + (size_t)N_ * NCB * 4)    // [N_][32] int    (2 MB)
#define OFF_EN  (OFF_PI + (size_t)N_ * NCB * 4)    // enorm [K_]
#define OFF_ZN  (OFF_EN + K_ * 4)                  // znorm [N_]
#define OFF_CNT (OFF_ZN + N_ * 4)                  // counts [K_]
#define OFF_BL  (OFF_CNT + K_ * 4)                 // blockLoss [4096]
#define OFF_ZH  (OFF_BL + 4096 * 4)                // zh packed [NKB][N_][32] f16 (16 MB)
#define OFF_ZL  (OFF_ZH + (size_t)N_ * D_ * 2)    // zl packed (16 MB)
#define OFF_EH  (OFF_ZL + (size_t)N_ * D_ * 2)    // eh packed [NKB][K_][32] (4 MB)
#define OFF_EL  (OFF_EH + (size_t)K_ * D_ * 2)    // el packed (4 MB)

// async 16B global->LDS (direct-to-shared DMA); lds dst is wave-uniform base + lane*16
__device__ __forceinline__ void load_lds16(const _Float16* g, _Float16* l) {
    __builtin_amdgcn_global_load_lds(
        (const __attribute__((address_space(1))) unsigned int*)(uintptr_t)g,
        (__attribute__((address_space(3))) unsigned int*)(uintptr_t)l,
        16, 0, 0);
}

// ---------------- kernel 1: row norms (kept BIT-IDENTICAL to round 2) ----------------
__global__ void vq_norms_kernel(const float* __restrict__ x, float* __restrict__ nrm) {
    int lane = threadIdx.x & 63;
    int row  = blockIdx.x * 4 + (threadIdx.x >> 6);
    const float* r = x + (size_t)row * D_;
    float s = 0.f;
    for (int j = lane; j < D_; j += 64) { float v = r[j]; s += v * v; }
    #pragma unroll
    for (int m = 1; m < 64; m <<= 1) s += __shfl_xor(s, m, 64);
    if (lane == 0) nrm[row] = s;
}

// ---------------- kernel 2: fp32 -> fp16 hi/lo split, packed K-block-major ----------------
// Layout: X[kb][row][32 halves]; within each 16-row group the four 16B chunks of a row
// are stored at position (qd ^ ((row>>1)&3)) — XOR swizzle so dist-kernel ds_read_b128
// lands on 2-way bank aliasing (free). Codebook scaled by 64 (exact) so lo stays normal.
__global__ __launch_bounds__(256)
void vq_presplit_kernel(const float* __restrict__ z, const float* __restrict__ cb,
                        _Float16* __restrict__ zh, _Float16* __restrict__ zl,
                        _Float16* __restrict__ eh, _Float16* __restrict__ el) {
    const size_t u = (size_t)blockIdx.x * 256 + threadIdx.x;
    const int c   = (int)(u & 63);     // chunk id 0..63 (8 consecutive k)
    const int row = (int)(u >> 6);     // 0..N_+K_-1
    const bool isZ = row < N_;
    const int n = isZ ? row : row - N_;
    const float* src = (isZ ? z : cb) + (size_t)n * D_ + c * 8;
    const float scale = isZ ? 1.0f : 64.0f;

    const float4 v0 = *(const float4*)src;
    const float4 v1 = *(const float4*)(src + 4);
    float a[8] = {v0.x, v0.y, v0.z, v0.w, v1.x, v1.y, v1.z, v1.w};
    half8 h, lo;
    #pragma unroll
    for (int j = 0; j < 8; j++) {
        const float x = a[j] * scale;
        const _Float16 hh = (_Float16)x;
        h[j]  = hh;
        lo[j] = (_Float16)(x - (float)hh);
    }
    const int kb = c >> 2, qd = c & 3;
    const int sw = qd ^ ((n >> 1) & 3);
    const size_t rows = isZ ? (size_t)N_ : (size_t)K_;
    const size_t off = (size_t)kb * rows * 32 + (size_t)n * 32 + (size_t)(sw << 3);
    *(half8*)((isZ ? zh : eh) + off) = h;
    *(half8*)((isZ ? zl : el) + off) = lo;
}

// ---------------- kernel 3: fused distance GEMM + per-tile argmin ----------------
// d[m][c] = fp32(fp32(znorm[m] + enorm[c]) - 2*dot) on np's fp32 lattice.
// dot = (zh*eh + zh*el + zl*eh) * 2^-6  (lo*lo term ~7e-8 on d: dropped).
__global__ __launch_bounds__(256, 2)
void vq_dist_kernel(const _Float16* __restrict__ zh, const _Float16* __restrict__ zl,
                    const _Float16* __restrict__ eh, const _Float16* __restrict__ el,
                    const float* __restrict__ enorm, const float* __restrict__ znorm,
                    float* __restrict__ pV, int* __restrict__ pI) {
    __shared__ _Float16 sAh[128 * 32], sAl[128 * 32];
    __shared__ _Float16 sBh[128 * 32], sBl[128 * 32];
    __shared__ float sE[128], sZn[128];
    __shared__ float candV[2][128];
    __shared__ int   candI[2][128];

    const int t  = threadIdx.x;
    const int m0 = blockIdx.x * 128;   // x fast: c-tile reuse across concurrent blocks
    const int c0 = blockIdx.y * 128;

    if (t < 128) { sE[t] = enorm[c0 + t]; sZn[t] = znorm[m0 + t]; }

    const int lane = t & 63, wid = t >> 6;
    const int wr = wid & 1, wc = wid >> 1;     // 2x2 waves over 128x128
    const int qd = lane >> 4, nl = lane & 15;
    const int sw8 = (qd ^ ((nl >> 1) & 3)) << 3;   // fragment-read swizzle (halves)

    // wave w stages array w: 0->Ah 1->Al 2->Bh 3->Bl; 8 x 1KB wave-loads per k-step
    const _Float16* gbase;
    _Float16* lbase;
    size_t gstride;
    if (wid == 0)      { gbase = zh + (size_t)m0 * 32; lbase = sAh; gstride = (size_t)N_ * 32; }
    else if (wid == 1) { gbase = zl + (size_t)m0 * 32; lbase = sAl; gstride = (size_t)N_ * 32; }
    else if (wid == 2) { gbase = eh + (size_t)c0 * 32; lbase = sBh; gstride = (size_t)K_ * 32; }
    else               { gbase = el + (size_t)c0 * 32; lbase = sBl; gstride = (size_t)K_ * 32; }
    const _Float16* gw = gbase + lane * 8;

    floatx4 acc[4][4];
    #pragma unroll
    for (int i = 0; i < 4; i++)
        #pragma unroll
        for (int j = 0; j < 4; j++) acc[i][j] = (floatx4)0.f;

    for (int kb = 0; kb < NKB; kb++) {
        __syncthreads();   // LDS safe from previous iteration's readers
        const _Float16* gk = gw + (size_t)kb * gstride;
        #pragma unroll
        for (int g = 0; g < 8; g++)
            load_lds16(gk + g * 512, lbase + g * 512);
        __syncthreads();   // implies s_waitcnt vmcnt(0): loads landed

        half8 a_h[4], a_l[4], b_h[4], b_l[4];
        #pragma unroll
        for (int s = 0; s < 4; s++) {
            const int ar = wr * 64 + s * 16 + nl;
            const int br = wc * 64 + s * 16 + nl;
            a_h[s] = *(const half8*)&sAh[ar * 32 + sw8];
            a_l[s] = *(const half8*)&sAl[ar * 32 + sw8];
            b_h[s] = *(const half8*)&sBh[br * 32 + sw8];
            b_l[s] = *(const half8*)&sBl[br * 32 + sw8];
        }
        #pragma unroll
        for (int i = 0; i < 4; i++)
            #pragma unroll
            for (int j = 0; j < 4; j++) {
                acc[i][j] = __builtin_amdgcn_mfma_f32_16x16x32_f16(a_h[i], b_h[j], acc[i][j], 0, 0, 0);
                acc[i][j] = __builtin_amdgcn_mfma_f32_16x16x32_f16(a_h[i], b_l[j], acc[i][j], 0, 0, 0);
                acc[i][j] = __builtin_amdgcn_mfma_f32_16x16x32_f16(a_l[i], b_h[j], acc[i][j], 0, 0, 0);
            }
    }

    // epilogue: identical rounding sequence to round 2 (np's fp32 lattice)
    #pragma unroll
    for (int sm = 0; sm < 4; sm++) {
        #pragma unroll
        for (int reg = 0; reg < 4; reg++) {
            const int rm = wr * 64 + sm * 16 + qd * 4 + reg;
            const float zn = sZn[rm];
            float bv = 1e30f; int bi = 0x7fffffff;
            #pragma unroll
            for (int sn = 0; sn < 4; sn++) {
                const int cl = wc * 64 + sn * 16 + nl;
                const float dot = acc[sm][sn][reg] * 0.015625f;  // /64, exact
                const float s2  = zn + sE[cl];                   // rounds once
                const float v   = s2 - 2.0f * dot;               // rounds once
                const int ci = c0 + cl;
                if (v < bv || (v == bv && ci < bi)) { bv = v; bi = ci; }
            }
            #pragma unroll
            for (int msk = 1; msk <= 8; msk <<= 1) {
                const float ov = __shfl_xor(bv, msk, 64);
                const int   oi = __shfl_xor(bi, msk, 64);
                if (ov < bv || (ov == bv && oi < bi)) { bv = ov; bi = oi; }
            }
            if (nl == 0) { candV[wc][rm] = bv; candI[wc][rm] = bi; }
        }
    }
    __syncthreads();
    if (t < 128) {
        float v0 = candV[0][t]; int i0 = candI[0][t];
        const float v1 = candV[1][t]; const int i1 = candI[1][t];
        if (v1 < v0 || (v1 == v0 && i1 < i0)) { v0 = v1; i0 = i1; }
        pV[(size_t)(m0 + t) * NCB + blockIdx.y] = v0;
        pI[(size_t)(m0 + t) * NCB + blockIdx.y] = i0;
    }
}

// ---------------- kernel 4: final argmin + gather + loss partials + histogram ----------------
__global__ __launch_bounds__(256)
void vq_gather_kernel(const float* __restrict__ z, const float* __restrict__ cb,
                      const float* __restrict__ pV, const int* __restrict__ pI,
                      float* __restrict__ out_zq, float* __restrict__ out_idx,
                      int* __restrict__ counts, float* __restrict__ blockLoss) {
    const int lane = threadIdx.x & 63, wid = threadIdx.x >> 6;
    const int m = blockIdx.x * 4 + wid;

    float v = 1e30f; int idx = 0x7fffffff;
    if (lane < NCB) { v = pV[(size_t)m * NCB + lane]; idx = pI[(size_t)m * NCB + lane]; }
    #pragma unroll
    for (int msk = 1; msk <= 16; msk <<= 1) {
        const float ov = __shfl_xor(v, msk, 64);
        const int   oi = __shfl_xor(idx, msk, 64);
        if (ov < v || (ov == v && oi < idx)) { v = ov; idx = oi; }
    }
    idx = __shfl(idx, 0, 64);

    const float4* qrow = (const float4*)(cb + (size_t)idx * D_);
    const float4* zrow = (const float4*)(z  + (size_t)m   * D_);
    float4*       orow = (float4*)(out_zq + (size_t)m * D_);
    float lsum = 0.f;
    #pragma unroll
    for (int i = 0; i < 2; i++) {
        const int j = lane + i * 64;
        const float4 q  = qrow[j];
        const float4 zv = zrow[j];
        float4 o;
        o.x = zv.x + (q.x - zv.x); o.y = zv.y + (q.y - zv.y);
        o.z = zv.z + (q.z - zv.z); o.w = zv.w + (q.w - zv.w);
        orow[j] = o;
        const float dx = zv.x - q.x, dy = zv.y - q.y, dz = zv.z - q.z, dw = zv.w - q.w;
        lsum += dx * dx + dy * dy + dz * dz + dw * dw;
    }
    #pragma unroll
    for (int msk = 1; msk < 64; msk <<= 1) lsum += __shfl_xor(lsum, msk, 64);

    if (lane == 0) {
        out_idx[m] = (float)idx;
        atomicAdd(&counts[idx], 1);
    }
    __shared__ float wl[4];
    if (lane == 0) wl[wid] = lsum;
    __syncthreads();
    if (threadIdx.x == 0) blockLoss[blockIdx.x] = wl[0] + wl[1] + wl[2] + wl[3];
}

// ---------------- kernel 5: scalars (loss, perplexity) ----------------
__global__ void vq_final_kernel(const int* __restrict__ counts,
                                const float* __restrict__ blockLoss,
                                float* __restrict__ out_loss, float* __restrict__ out_ppl) {
    __shared__ float sl[256], se[256];
    const int t = threadIdx.x;
    float ls = 0.f, es = 0.f;
    for (int i = t; i < N_ / 4; i += 256) ls += blockLoss[i];
    for (int k = t; k < K_; k += 256) {
        const float p = (float)counts[k] / (float)N_;
        es += p * logf(p + 1e-10f);
    }
    sl[t] = ls; se[t] = es;
    __syncthreads();
    for (int s = 128; s > 0; s >>= 1) {
        if (t < s) { sl[t] += sl[t + s]; se[t] += se[t + s]; }
        __syncthreads();
    }
    if (t == 0) {
        out_loss[0] = 0.25f * (sl[0] / (float)((size_t)N_ * D_));
        out_ppl[0]  = expf(-se[0]);
    }
}

extern "C" void kernel_launch(void* const* d_in, const int* in_sizes, int n_in,
                              void* d_out, int out_size, void* d_ws, size_t ws_size,
                              hipStream_t stream) {
    const float* z  = (const float*)d_in[0];
    const float* cb = (const float*)d_in[1];
    float* out = (float*)d_out;

    char* ws = (char*)d_ws;
    float*    pV        = (float*)   (ws + OFF_PV);
    int*      pI        = (int*)     (ws + OFF_PI);
    float*    enorm     = (float*)   (ws + OFF_EN);
    float*    znorm     = (float*)   (ws + OFF_ZN);
    int*      counts    = (int*)     (ws + OFF_CNT);
    float*    blockLoss = (float*)   (ws + OFF_BL);
    _Float16* zh        = (_Float16*)(ws + OFF_ZH);
    _Float16* zl        = (_Float16*)(ws + OFF_ZL);
    _Float16* eh        = (_Float16*)(ws + OFF_EH);
    _Float16* el        = (_Float16*)(ws + OFF_EL);

    float* out_zq   = out;                         // [N_*D_]
    float* out_loss = out + (size_t)N_ * D_;       // [1]
    float* out_idx  = out_loss + 1;                // [N_]
    float* out_ppl  = out_idx + N_;                // [1]

    hipMemsetAsync(counts, 0, K_ * sizeof(int), stream);

    vq_norms_kernel<<<K_ / 4, 256, 0, stream>>>(cb, enorm);
    vq_norms_kernel<<<N_ / 4, 256, 0, stream>>>(z, znorm);

    vq_presplit_kernel<<<(N_ + K_) * 64 / 256, 256, 0, stream>>>(z, cb, zh, zl, eh, el);

    dim3 grid(N_ / 128, K_ / 128);
    vq_dist_kernel<<<grid, 256, 0, stream>>>(zh, zl, eh, el, enorm, znorm, pV, pI);

    vq_gather_kernel<<<N_ / 4, 256, 0, stream>>>(z, cb, pV, pI, out_zq, out_idx,
                                                 counts, blockLoss);

    vq_final_kernel<<<1, 256, 0, stream>>>(counts, blockLoss, out_loss, out_ppl);
}